// Round 5
// baseline (448.021 us; speedup 1.0000x reference)
//
#include <hip/hip_runtime.h>

typedef unsigned short u16;
typedef unsigned int u32;
typedef __attribute__((ext_vector_type(8))) __bf16 bf16x8;
typedef __attribute__((ext_vector_type(4))) float f32x4;

#define BK 32

__device__ __forceinline__ u16 f2bf(float x) {
    u32 u = __float_as_uint(x);
    u = (u + 0x7FFFu + ((u >> 16) & 1u)) >> 16;
    return (u16)u;
}
__device__ __forceinline__ float bf2f(u16 h) { return __uint_as_float(((u32)h) << 16); }

#define GLD16(g, l)                                                                        \
    __builtin_amdgcn_global_load_lds((const __attribute__((address_space(1))) void*)(g),   \
                                     (__attribute__((address_space(3))) void*)(l), 16, 0, 0)

// ---------------- elementwise fp32 -> bf16 hi/lo split (big inputs) ----------------
__global__ __launch_bounds__(256) void split2_k(const float* __restrict__ x,
                                                u16* __restrict__ h, u16* __restrict__ l,
                                                long n4) {
    long i = (long)blockIdx.x * 256 + threadIdx.x;
    if (i >= n4) return;
    float4 v = ((const float4*)x)[i];
    float xs[4] = {v.x, v.y, v.z, v.w};
    u16 hh[4], ll[4];
#pragma unroll
    for (int q = 0; q < 4; ++q) {
        hh[q] = f2bf(xs[q]);
        ll[q] = f2bf(xs[q] - bf2f(hh[q]));
    }
    uint2 ph, pl;
    ph.x = hh[0] | ((u32)hh[1] << 16); ph.y = hh[2] | ((u32)hh[3] << 16);
    pl.x = ll[0] | ((u32)ll[1] << 16); pl.y = ll[2] | ((u32)ll[3] << 16);
    ((uint2*)h)[i] = ph;
    ((uint2*)l)[i] = pl;
}

// ---------------- ALL weight prep fused in one dispatch (grid = 1026 blocks) ----------------
// bid 0..255: split Wq -> Wqh/Wql (orig layout). 256..511: split Wk.
// 512..767: transpose Wv -> WvTh (bf16 hi). 768..1023: transpose Wo -> WoTh.
// 1024..1025: u2 = Wk @ bq (contract attn dim).
__global__ __launch_bounds__(256) void prep_weights_k(
    const float* __restrict__ Wq, const float* __restrict__ Wk,
    const float* __restrict__ Wv, const float* __restrict__ Wo,
    const float* __restrict__ bq,
    u16* __restrict__ Wqh, u16* __restrict__ Wql,
    u16* __restrict__ Wkh, u16* __restrict__ Wkl,
    u16* __restrict__ WvTh, u16* __restrict__ WoTh,
    float* __restrict__ u2, int dim) {
    __shared__ float tile[32][33];
    const int bid = blockIdx.x, t = threadIdx.x;
    if (bid < 512) {
        const float* src = bid < 256 ? Wq : Wk;
        u16* dh = bid < 256 ? Wqh : Wkh;
        u16* dl = bid < 256 ? Wql : Wkl;
        long i = (long)(bid & 255) * 256 + t;
        float4 v = ((const float4*)src)[i];
        float xs[4] = {v.x, v.y, v.z, v.w};
        u16 hh[4], ll[4];
#pragma unroll
        for (int q = 0; q < 4; ++q) {
            hh[q] = f2bf(xs[q]);
            ll[q] = f2bf(xs[q] - bf2f(hh[q]));
        }
        uint2 ph, pl;
        ph.x = hh[0] | ((u32)hh[1] << 16); ph.y = hh[2] | ((u32)hh[3] << 16);
        pl.x = ll[0] | ((u32)ll[1] << 16); pl.y = ll[2] | ((u32)ll[3] << 16);
        ((uint2*)dh)[i] = ph;
        ((uint2*)dl)[i] = pl;
    } else if (bid < 1024) {
        const float* src = bid < 768 ? Wv : Wo;
        u16* dst = bid < 768 ? WvTh : WoTh;
        const int b2 = (bid - 512) & 255;
        const int bx = (b2 & 15) * 32, by = (b2 >> 4) * 32;
        const int tx = t & 31, ty = t >> 5;
        for (int i = 0; i < 32; i += 8)
            tile[ty + i][tx] = src[(size_t)(by + ty + i) * dim + bx + tx];
        __syncthreads();
        for (int i = 0; i < 32; i += 8)
            dst[(size_t)(bx + ty + i) * dim + by + tx] = f2bf(tile[tx][ty + i]);
    } else {
        const int d = (bid - 1024) * 256 + t;
        const float* wr = Wk + (long)d * dim;
        float s = 0.f;
        for (int c = 0; c < dim; c += 4) {
            float4 w4 = *(const float4*)(wr + c);
            float4 b4 = *(const float4*)(bq + c);
            s += w4.x * b4.x + w4.y * b4.y + w4.z * b4.z + w4.w * b4.w;
        }
        u2[d] = s;
    }
}

// outv[row] = scale * (X[row,:] . u)   (wave per row; 4 rows per block)
__global__ __launch_bounds__(256) void rowdot_k(const float* __restrict__ X,
                                                const float* __restrict__ u,
                                                float* __restrict__ outv, int K,
                                                float scale) {
    const int row = blockIdx.x * 4 + (threadIdx.x >> 6);
    const int lane = threadIdx.x & 63;
    const float4* xr = (const float4*)(X + (long)row * K);
    const float4* ur = (const float4*)u;
    float4 a0 = xr[lane * 2], a1 = xr[lane * 2 + 1];
    float4 b0 = ur[lane * 2], b1 = ur[lane * 2 + 1];
    float s = a0.x * b0.x + a0.y * b0.y + a0.z * b0.z + a0.w * b0.w +
              a1.x * b1.x + a1.y * b1.y + a1.z * b1.z + a1.w * b1.w;
#pragma unroll
    for (int o = 32; o; o >>= 1) s += __shfl_xor(s, o);
    if (!lane) outv[row] = s * scale;
}

// ---------------- row softmax with column-bias, fp32 in, bf16 out in place ----------------
__global__ __launch_bounds__(256) void softmax_k(float* __restrict__ S,
                                                 const float* __restrict__ beta, int N) {
    const long r = blockIdx.x;
    float* row = S + r * N;
    const float* brow = beta + (r / N) * N;
    const int t = threadIdx.x;
    float4 va = ((const float4*)row)[2 * t];
    float4 vb = ((const float4*)row)[2 * t + 1];
    float4 ba = ((const float4*)brow)[2 * t];
    float4 bb = ((const float4*)brow)[2 * t + 1];
    float v[8] = {va.x + ba.x, va.y + ba.y, va.z + ba.z, va.w + ba.w,
                  vb.x + bb.x, vb.y + bb.y, vb.z + bb.z, vb.w + bb.w};
    float m = v[0];
#pragma unroll
    for (int i = 1; i < 8; i++) m = fmaxf(m, v[i]);
#pragma unroll
    for (int o = 32; o; o >>= 1) m = fmaxf(m, __shfl_xor(m, o));
    __shared__ float smax[4], ssum[4];
    if ((t & 63) == 0) smax[t >> 6] = m;
    __syncthreads();
    m = fmaxf(fmaxf(smax[0], smax[1]), fmaxf(smax[2], smax[3]));
    float s = 0.f;
#pragma unroll
    for (int i = 0; i < 8; i++) { v[i] = __expf(v[i] - m); s += v[i]; }
#pragma unroll
    for (int o = 32; o; o >>= 1) s += __shfl_xor(s, o);
    if ((t & 63) == 0) ssum[t >> 6] = s;
    __syncthreads();
    s = ssum[0] + ssum[1] + ssum[2] + ssum[3];
    const float inv = 1.0f / s;
    u32 w0 = f2bf(v[0] * inv) | ((u32)f2bf(v[1] * inv) << 16);
    u32 w1 = f2bf(v[2] * inv) | ((u32)f2bf(v[3] * inv) << 16);
    u32 w2 = f2bf(v[4] * inv) | ((u32)f2bf(v[5] * inv) << 16);
    u32 w3 = f2bf(v[6] * inv) | ((u32)f2bf(v[7] * inv) << 16);
    uint4 o4; o4.x = w0; o4.y = w1; o4.z = w2; o4.w = w3;
    ((uint4*)row)[t] = o4;
}

// ---------------- MFMA GEMM, C = A @ BT^T, global_load_lds + XOR-swizzled LDS ----------------
template <int SPLIT, int BMt, int BNt, int WR, int WC>
__global__ __launch_bounds__(256) void gemm_k(
    const u16* __restrict__ Ah, const u16* __restrict__ Al, long lda, long strideA,
    const u16* __restrict__ BTh, const u16* __restrict__ BTl, long ldb, long strideBT,
    const float* __restrict__ bias1, const float* __restrict__ bias2, int nsplit,
    const float* __restrict__ resid, long ldres, float scale,
    float* __restrict__ Cf, long ldcf,
    u16* __restrict__ Cbh, u16* __restrict__ Cbl, long ldcb,
    u16* __restrict__ CbT, long tRows, long tChans, long ldct,
    long strideC, int K) {
    static_assert(WR * WC == 4, "4 waves");
    constexpr int MI = BMt / WR / 16;
    constexpr int NJ = BNt / WC / 16;
    constexpr int PA = BMt / 64;
    constexpr int PB = BNt / 64;

    __shared__ u16 AsH[BMt * BK];
    __shared__ u16 BsH[BNt * BK];
    __shared__ u16 AsL[(SPLIT ? BMt : 1) * BK];
    __shared__ u16 BsL[(SPLIT ? BNt : 1) * BK];

    const long bz = blockIdx.z;
    Ah += bz * strideA;
    BTh += bz * strideBT;
    if constexpr (SPLIT) { Al += bz * strideA; BTl += bz * strideBT; }
    if (Cf) Cf += bz * strideC;
    if (Cbh) Cbh += bz * strideC;
    if (Cbl) Cbl += bz * strideC;

    const int t = threadIdx.x;
    const int w = t >> 6, lane = t & 63;
    const int l15 = lane & 15, quad = lane >> 4;
    const int m0 = blockIdx.x * BMt, n0 = blockIdx.y * BNt;
    const int wrow = (w / WC) * (BMt / WR);
    const int wcol = (w % WC) * (BNt / WC);

    const u16* gAh[PA]; const u16* gAl[PA]; int lA[PA];
    const u16* gBh[PB]; const u16* gBl[PB]; int lB[PB];
#pragma unroll
    for (int p = 0; p < PA; ++p) {
        int slot = p * 256 + t;
        int r = slot >> 2, c = slot & 3;
        int cg = c ^ ((r >> 1) & 3);
        gAh[p] = Ah + (long)(m0 + r) * lda + cg * 8;
        if constexpr (SPLIT) gAl[p] = Al + (long)(m0 + r) * lda + cg * 8;
        lA[p] = (p * 256 + w * 64) * 8;
    }
#pragma unroll
    for (int p = 0; p < PB; ++p) {
        int slot = p * 256 + t;
        int r = slot >> 2, c = slot & 3;
        int cg = c ^ ((r >> 1) & 3);
        gBh[p] = BTh + (long)(n0 + r) * ldb + cg * 8;
        if constexpr (SPLIT) gBl[p] = BTl + (long)(n0 + r) * ldb + cg * 8;
        lB[p] = (p * 256 + w * 64) * 8;
    }

    int aoff[MI], boff[NJ];
#pragma unroll
    for (int i = 0; i < MI; ++i) {
        int r = wrow + i * 16 + l15;
        aoff[i] = (r * 4 + (quad ^ ((r >> 1) & 3))) * 8;
    }
#pragma unroll
    for (int j = 0; j < NJ; ++j) {
        int r = wcol + j * 16 + l15;
        boff[j] = (r * 4 + (quad ^ ((r >> 1) & 3))) * 8;
    }

    f32x4 acc[MI][NJ];
#pragma unroll
    for (int i = 0; i < MI; i++)
#pragma unroll
        for (int j = 0; j < NJ; j++) acc[i][j] = (f32x4){0.f, 0.f, 0.f, 0.f};

    for (int k0 = 0; k0 < K; k0 += BK) {
#pragma unroll
        for (int p = 0; p < PA; ++p) {
            GLD16(gAh[p], AsH + lA[p]);
            gAh[p] += BK;
            if constexpr (SPLIT) { GLD16(gAl[p], AsL + lA[p]); gAl[p] += BK; }
        }
#pragma unroll
        for (int p = 0; p < PB; ++p) {
            GLD16(gBh[p], BsH + lB[p]);
            gBh[p] += BK;
            if constexpr (SPLIT) { GLD16(gBl[p], BsL + lB[p]); gBl[p] += BK; }
        }
        __syncthreads();

        bf16x8 aH[MI], bH[NJ];
#pragma unroll
        for (int i = 0; i < MI; ++i) aH[i] = *(const bf16x8*)&AsH[aoff[i]];
#pragma unroll
        for (int j = 0; j < NJ; ++j) bH[j] = *(const bf16x8*)&BsH[boff[j]];
        if constexpr (SPLIT) {
            bf16x8 aL[MI], bL[NJ];
#pragma unroll
            for (int i = 0; i < MI; ++i) aL[i] = *(const bf16x8*)&AsL[aoff[i]];
#pragma unroll
            for (int j = 0; j < NJ; ++j) bL[j] = *(const bf16x8*)&BsL[boff[j]];
#pragma unroll
            for (int i = 0; i < MI; ++i)
#pragma unroll
                for (int j = 0; j < NJ; ++j) {
                    acc[i][j] = __builtin_amdgcn_mfma_f32_16x16x32_bf16(aH[i], bH[j], acc[i][j], 0, 0, 0);
                    acc[i][j] = __builtin_amdgcn_mfma_f32_16x16x32_bf16(aH[i], bL[j], acc[i][j], 0, 0, 0);
                    acc[i][j] = __builtin_amdgcn_mfma_f32_16x16x32_bf16(aL[i], bH[j], acc[i][j], 0, 0, 0);
                }
        } else {
#pragma unroll
            for (int i = 0; i < MI; ++i)
#pragma unroll
                for (int j = 0; j < NJ; ++j)
                    acc[i][j] = __builtin_amdgcn_mfma_f32_16x16x32_bf16(aH[i], bH[j], acc[i][j], 0, 0, 0);
        }
        __syncthreads();
    }

    // epilogue: C/D layout col=lane&15, row=quad*4+reg
#pragma unroll
    for (int i = 0; i < MI; ++i) {
#pragma unroll
        for (int j = 0; j < NJ; ++j) {
            const int mBase = m0 + wrow + i * 16 + quad * 4;
            const int nn = n0 + wcol + j * 16 + l15;
            const bool norm = nn < nsplit;
            float bvs;
            if (norm) bvs = bias1 ? bias1[nn] : 0.f;
            else bvs = bias2 ? bias2[nn - nsplit] : 0.f;
#pragma unroll
            for (int r = 0; r < 4; ++r) {
                const long row = mBase + r;
                float x = acc[i][j][r] * scale + bvs;
                if (resid) x += resid[row * ldres + nn];
                if (norm) {
                    if (Cf) Cf[row * ldcf + nn] = x;
                    if (Cbh) {
                        u16 h = f2bf(x);
                        Cbh[row * ldcb + nn] = h;
                        if (Cbl) Cbl[row * ldcb + nn] = f2bf(x - bf2f(h));
                    }
                } else {
                    long b = row / tRows, q = row - b * tRows;
                    CbT[(b * tChans + (nn - nsplit)) * ldct + q] = f2bf(x);
                }
            }
        }
    }
}

extern "C" void kernel_launch(void* const* d_in, const int* in_sizes, int n_in,
                              void* d_out, int out_size, void* d_ws, size_t ws_size,
                              hipStream_t stream) {
    const float* query = (const float*)d_in[0];
    const float* kv    = (const float*)d_in[1];
    const float* Wq = (const float*)d_in[2];
    const float* bq = (const float*)d_in[3];
    const float* Wk = (const float*)d_in[4];
    const float* Wv = (const float*)d_in[6];
    const float* bv = (const float*)d_in[7];
    const float* Wo = (const float*)d_in[8];
    const float* bo = (const float*)d_in[9];
    float* out = (float*)d_out;

    const int B = 4, N = 2048, D = 512;
    const long MD = (long)B * N * D;  // 4,194,304 (8192 rows x 512)
    const long DD = (long)D * D;
    const int BIG = 1 << 30;

    char* p = (char*)d_ws;
    auto alloc = [&](size_t bytes) { void* r = (void*)p; p += (bytes + 255) & ~(size_t)255; return r; };
    float* S = (float*)alloc((long)B * N * N * 4);   // 67 MB; Xq hi/lo splits alias first 33.5 MB
    u16* QXh = (u16*)S;                               // dead before S is written
    u16* QXl = QXh + MD;
    u16* KVh = (u16*)alloc(MD * 2);                   // alive through S-GEMM + Vproj
    u16* KVl = (u16*)alloc(MD * 2);
    u16* Th  = (u16*)alloc(MD * 2);                   // T = Xq @ G, hi/lo
    u16* Tl  = (u16*)alloc(MD * 2);
    u16* Vt  = (u16*)alloc(MD * 2);                   // [B][D][N]
    u16* Oh  = (u16*)alloc(MD * 2);
    u16* Wqh = (u16*)alloc(DD * 2);                   // split(Wq), ORIGINAL [d][a] layout
    u16* Wql = (u16*)alloc(DD * 2);
    u16* Wkh = (u16*)alloc(DD * 2);
    u16* Wkl = (u16*)alloc(DD * 2);
    u16* WvTh = (u16*)alloc(DD * 2);
    u16* WoTh = (u16*)alloc(DD * 2);
    u16* MTh  = (u16*)alloc(DD * 2);                  // MT[n][k] = G[k][n], G = Wq·Wk^T
    u16* MTl  = (u16*)alloc(DD * 2);
    float* u2 = (float*)alloc(D * 4);
    float* betav = (float*)alloc((long)B * N * 4);    // SCALE * Xk·(Wk bq)

    const dim3 blk(256, 1, 1);
    const float SCALE = 22.627416997969522f;  // sqrt(512), multiplied per reference

    // big input splits + fused weight prep + beta
    split2_k<<<dim3(4096, 1, 1), blk, 0, stream>>>(query, QXh, QXl, MD / 4);
    split2_k<<<dim3(4096, 1, 1), blk, 0, stream>>>(kv, KVh, KVl, MD / 4);
    prep_weights_k<<<dim3(1026, 1, 1), blk, 0, stream>>>(
        Wq, Wk, Wv, Wo, bq, Wqh, Wql, Wkh, Wkl, WvTh, WoTh, u2, D);
    rowdot_k<<<dim3(2048, 1, 1), blk, 0, stream>>>(kv, u2, betav, D, SCALE);

    // MT = Wk @ Wq^T over attn dim: MT[n][k] = sum_a Wk[n][a]·Wq[k][a] = G[k][n]
    gemm_k<1, 64, 64, 2, 2><<<dim3(8, 8, 1), blk, 0, stream>>>(
        Wkh, Wkl, D, 0,
        Wqh, Wql, D, 0,
        nullptr, nullptr, BIG,
        nullptr, 0, 1.0f,
        nullptr, 0,
        MTh, MTl, D,
        nullptr, 1, 1, 1,
        0, D);
    // T = Xq @ G  (split): BT[n][k] = G[k][n] = MT
    gemm_k<1, 128, 128, 2, 2><<<dim3(64, 4, 1), blk, 0, stream>>>(
        QXh, QXl, D, 0,
        MTh, MTl, D, 0,
        nullptr, nullptr, BIG,
        nullptr, 0, 1.0f,
        nullptr, 0,
        Th, Tl, D,
        nullptr, 1, 1, 1,
        0, D);
    // V = Xk @ Wv + bv  (plain bf16), written transposed per batch: Vt[b][c][q]
    gemm_k<0, 128, 128, 2, 2><<<dim3(64, 4, 1), blk, 0, stream>>>(
        KVh, nullptr, D, 0,
        WvTh, nullptr, D, 0,
        nullptr, bv, 0,
        nullptr, 0, 1.0f,
        nullptr, 0,
        nullptr, nullptr, 0,
        Vt, (long)N, (long)D, (long)N,
        0, D);
    // S = SCALE * (T @ Xk^T)   (split; beta_j added in softmax, alpha_i cancels)
    gemm_k<1, 128, 128, 2, 2><<<dim3(16, 16, 4), blk, 0, stream>>>(
        Th, Tl, D, (long)N * D,
        KVh, KVl, D, (long)N * D,
        nullptr, nullptr, BIG,
        nullptr, 0, SCALE,
        S, N,
        nullptr, nullptr, 0,
        nullptr, 1, 1, 1,
        (long)N * N, D);
    // softmax rows (+beta_j), bf16 P in place
    softmax_k<<<dim3(B * N, 1, 1), blk, 0, stream>>>(S, betav, N);
    // O = P @ V  (A = bf16 P rows at pitch 2N u16; BT = Vt; K=2048 -> 64 k-steps)
    gemm_k<0, 128, 128, 2, 2><<<dim3(16, 4, 4), blk, 0, stream>>>(
        (const u16*)S, nullptr, 2L * N, (long)N * 2 * N,
        Vt, nullptr, N, (long)D * N,
        nullptr, nullptr, BIG,
        nullptr, 0, 1.0f,
        nullptr, 0,
        Oh, nullptr, D,
        nullptr, 1, 1, 1,
        (long)N * D, N);
    // out = query + O @ Wo + bo
    gemm_k<0, 128, 128, 2, 2><<<dim3(64, 4, 1), blk, 0, stream>>>(
        Oh, nullptr, D, 0,
        WoTh, nullptr, D, 0,
        bo, nullptr, BIG,
        query, D, 1.0f,
        out, D,
        nullptr, nullptr, 0,
        nullptr, 1, 1, 1,
        0, D);
    (void)in_sizes; (void)n_in; (void)out_size; (void)ws_size;
}

// Round 6
// 391.794 us; speedup vs baseline: 1.1435x; 1.1435x over previous
//
#include <hip/hip_runtime.h>

typedef unsigned short u16;
typedef unsigned int u32;
typedef __attribute__((ext_vector_type(8))) __bf16 bf16x8;
typedef __attribute__((ext_vector_type(4))) float f32x4;

#define BK 32

__device__ __forceinline__ u16 f2bf(float x) {
    u32 u = __float_as_uint(x);
    u = (u + 0x7FFFu + ((u >> 16) & 1u)) >> 16;
    return (u16)u;
}
__device__ __forceinline__ float bf2f(u16 h) { return __uint_as_float(((u32)h) << 16); }

#define GLD16(g, l)                                                                        \
    __builtin_amdgcn_global_load_lds((const __attribute__((address_space(1))) void*)(g),   \
                                     (__attribute__((address_space(3))) void*)(l), 16, 0, 0)

// ---------------- both big inputs split in ONE dispatch (grid = 2*n4/256) ----------------
__global__ __launch_bounds__(256) void split2x2_k(const float* __restrict__ x0,
                                                  u16* __restrict__ h0, u16* __restrict__ l0,
                                                  const float* __restrict__ x1,
                                                  u16* __restrict__ h1, u16* __restrict__ l1,
                                                  long n4) {
    long i = (long)blockIdx.x * 256 + threadIdx.x;
    const float* x; u16* h; u16* l;
    if (i < n4) { x = x0; h = h0; l = l0; }
    else { x = x1; h = h1; l = l1; i -= n4; }
    float4 v = ((const float4*)x)[i];
    float xs[4] = {v.x, v.y, v.z, v.w};
    u16 hh[4], ll[4];
#pragma unroll
    for (int q = 0; q < 4; ++q) {
        hh[q] = f2bf(xs[q]);
        ll[q] = f2bf(xs[q] - bf2f(hh[q]));
    }
    uint2 ph, pl;
    ph.x = hh[0] | ((u32)hh[1] << 16); ph.y = hh[2] | ((u32)hh[3] << 16);
    pl.x = ll[0] | ((u32)ll[1] << 16); pl.y = ll[2] | ((u32)ll[3] << 16);
    ((uint2*)h)[i] = ph;
    ((uint2*)l)[i] = pl;
}

// ---------------- ALL weight prep fused in one dispatch (grid = 1026 blocks) ----------------
__global__ __launch_bounds__(256) void prep_weights_k(
    const float* __restrict__ Wq, const float* __restrict__ Wk,
    const float* __restrict__ Wv, const float* __restrict__ Wo,
    const float* __restrict__ bq,
    u16* __restrict__ Wqh, u16* __restrict__ Wql,
    u16* __restrict__ Wkh, u16* __restrict__ Wkl,
    u16* __restrict__ WvTh, u16* __restrict__ WoTh,
    float* __restrict__ u2, int dim) {
    __shared__ float tile[32][33];
    const int bid = blockIdx.x, t = threadIdx.x;
    if (bid < 512) {
        const float* src = bid < 256 ? Wq : Wk;
        u16* dh = bid < 256 ? Wqh : Wkh;
        u16* dl = bid < 256 ? Wql : Wkl;
        long i = (long)(bid & 255) * 256 + t;
        float4 v = ((const float4*)src)[i];
        float xs[4] = {v.x, v.y, v.z, v.w};
        u16 hh[4], ll[4];
#pragma unroll
        for (int q = 0; q < 4; ++q) {
            hh[q] = f2bf(xs[q]);
            ll[q] = f2bf(xs[q] - bf2f(hh[q]));
        }
        uint2 ph, pl;
        ph.x = hh[0] | ((u32)hh[1] << 16); ph.y = hh[2] | ((u32)hh[3] << 16);
        pl.x = ll[0] | ((u32)ll[1] << 16); pl.y = ll[2] | ((u32)ll[3] << 16);
        ((uint2*)dh)[i] = ph;
        ((uint2*)dl)[i] = pl;
    } else if (bid < 1024) {
        const float* src = bid < 768 ? Wv : Wo;
        u16* dst = bid < 768 ? WvTh : WoTh;
        const int b2 = (bid - 512) & 255;
        const int bx = (b2 & 15) * 32, by = (b2 >> 4) * 32;
        const int tx = t & 31, ty = t >> 5;
        for (int i = 0; i < 32; i += 8)
            tile[ty + i][tx] = src[(size_t)(by + ty + i) * dim + bx + tx];
        __syncthreads();
        for (int i = 0; i < 32; i += 8)
            dst[(size_t)(bx + ty + i) * dim + by + tx] = f2bf(tile[tx][ty + i]);
    } else {
        const int d = (bid - 1024) * 256 + t;
        const float* wr = Wk + (long)d * dim;
        float s = 0.f;
        for (int c = 0; c < dim; c += 4) {
            float4 w4 = *(const float4*)(wr + c);
            float4 b4 = *(const float4*)(bq + c);
            s += w4.x * b4.x + w4.y * b4.y + w4.z * b4.z + w4.w * b4.w;
        }
        u2[d] = s;
    }
}

// outv[row] = scale * (X[row,:] . u)   (wave per row; 4 rows per block)
__global__ __launch_bounds__(256) void rowdot_k(const float* __restrict__ X,
                                                const float* __restrict__ u,
                                                float* __restrict__ outv, int K,
                                                float scale) {
    const int row = blockIdx.x * 4 + (threadIdx.x >> 6);
    const int lane = threadIdx.x & 63;
    const float4* xr = (const float4*)(X + (long)row * K);
    const float4* ur = (const float4*)u;
    float4 a0 = xr[lane * 2], a1 = xr[lane * 2 + 1];
    float4 b0 = ur[lane * 2], b1 = ur[lane * 2 + 1];
    float s = a0.x * b0.x + a0.y * b0.y + a0.z * b0.z + a0.w * b0.w +
              a1.x * b1.x + a1.y * b1.y + a1.z * b1.z + a1.w * b1.w;
#pragma unroll
    for (int o = 32; o; o >>= 1) s += __shfl_xor(s, o);
    if (!lane) outv[row] = s * scale;
}

// ---------------- row softmax with column-bias, fp32 in, bf16 out in place ----------------
__global__ __launch_bounds__(256) void softmax_k(float* __restrict__ S,
                                                 const float* __restrict__ beta, int N) {
    const long r = blockIdx.x;
    float* row = S + r * N;
    const float* brow = beta + (r / N) * N;
    const int t = threadIdx.x;
    float4 va = ((const float4*)row)[2 * t];
    float4 vb = ((const float4*)row)[2 * t + 1];
    float4 ba = ((const float4*)brow)[2 * t];
    float4 bb = ((const float4*)brow)[2 * t + 1];
    float v[8] = {va.x + ba.x, va.y + ba.y, va.z + ba.z, va.w + ba.w,
                  vb.x + bb.x, vb.y + bb.y, vb.z + bb.z, vb.w + bb.w};
    float m = v[0];
#pragma unroll
    for (int i = 1; i < 8; i++) m = fmaxf(m, v[i]);
#pragma unroll
    for (int o = 32; o; o >>= 1) m = fmaxf(m, __shfl_xor(m, o));
    __shared__ float smax[4], ssum[4];
    if ((t & 63) == 0) smax[t >> 6] = m;
    __syncthreads();
    m = fmaxf(fmaxf(smax[0], smax[1]), fmaxf(smax[2], smax[3]));
    float s = 0.f;
#pragma unroll
    for (int i = 0; i < 8; i++) { v[i] = __expf(v[i] - m); s += v[i]; }
#pragma unroll
    for (int o = 32; o; o >>= 1) s += __shfl_xor(s, o);
    if ((t & 63) == 0) ssum[t >> 6] = s;
    __syncthreads();
    s = ssum[0] + ssum[1] + ssum[2] + ssum[3];
    const float inv = 1.0f / s;
    u32 w0 = f2bf(v[0] * inv) | ((u32)f2bf(v[1] * inv) << 16);
    u32 w1 = f2bf(v[2] * inv) | ((u32)f2bf(v[3] * inv) << 16);
    u32 w2 = f2bf(v[4] * inv) | ((u32)f2bf(v[5] * inv) << 16);
    u32 w3 = f2bf(v[6] * inv) | ((u32)f2bf(v[7] * inv) << 16);
    uint4 o4; o4.x = w0; o4.y = w1; o4.z = w2; o4.w = w3;
    ((uint4*)row)[t] = o4;
}

// ---------------- MFMA GEMM, C = A @ BT^T, global_load_lds + XOR-swizzled LDS ----------------
template <int SPLIT, int BMt, int BNt, int WR, int WC>
__global__ __launch_bounds__(256) void gemm_k(
    const u16* __restrict__ Ah, const u16* __restrict__ Al, long lda, long strideA,
    const u16* __restrict__ BTh, const u16* __restrict__ BTl, long ldb, long strideBT,
    const float* __restrict__ bias1, const float* __restrict__ bias2, int nsplit,
    const float* __restrict__ resid, long ldres, float scale,
    float* __restrict__ Cf, long ldcf,
    u16* __restrict__ Cbh, u16* __restrict__ Cbl, long ldcb,
    u16* __restrict__ CbT, long tRows, long tChans, long ldct,
    long strideC, int K) {
    static_assert(WR * WC == 4, "4 waves");
    constexpr int MI = BMt / WR / 16;
    constexpr int NJ = BNt / WC / 16;
    constexpr int PA = BMt / 64;
    constexpr int PB = BNt / 64;

    __shared__ u16 AsH[BMt * BK];
    __shared__ u16 BsH[BNt * BK];
    __shared__ u16 AsL[(SPLIT ? BMt : 1) * BK];
    __shared__ u16 BsL[(SPLIT ? BNt : 1) * BK];

    const long bz = blockIdx.z;
    Ah += bz * strideA;
    BTh += bz * strideBT;
    if constexpr (SPLIT) { Al += bz * strideA; BTl += bz * strideBT; }
    if (Cf) Cf += bz * strideC;
    if (Cbh) Cbh += bz * strideC;
    if (Cbl) Cbl += bz * strideC;

    const int t = threadIdx.x;
    const int w = t >> 6, lane = t & 63;
    const int l15 = lane & 15, quad = lane >> 4;
    const int m0 = blockIdx.x * BMt, n0 = blockIdx.y * BNt;
    const int wrow = (w / WC) * (BMt / WR);
    const int wcol = (w % WC) * (BNt / WC);

    const u16* gAh[PA]; const u16* gAl[PA]; int lA[PA];
    const u16* gBh[PB]; const u16* gBl[PB]; int lB[PB];
#pragma unroll
    for (int p = 0; p < PA; ++p) {
        int slot = p * 256 + t;
        int r = slot >> 2, c = slot & 3;
        int cg = c ^ ((r >> 1) & 3);
        gAh[p] = Ah + (long)(m0 + r) * lda + cg * 8;
        if constexpr (SPLIT) gAl[p] = Al + (long)(m0 + r) * lda + cg * 8;
        lA[p] = (p * 256 + w * 64) * 8;
    }
#pragma unroll
    for (int p = 0; p < PB; ++p) {
        int slot = p * 256 + t;
        int r = slot >> 2, c = slot & 3;
        int cg = c ^ ((r >> 1) & 3);
        gBh[p] = BTh + (long)(n0 + r) * ldb + cg * 8;
        if constexpr (SPLIT) gBl[p] = BTl + (long)(n0 + r) * ldb + cg * 8;
        lB[p] = (p * 256 + w * 64) * 8;
    }

    int aoff[MI], boff[NJ];
#pragma unroll
    for (int i = 0; i < MI; ++i) {
        int r = wrow + i * 16 + l15;
        aoff[i] = (r * 4 + (quad ^ ((r >> 1) & 3))) * 8;
    }
#pragma unroll
    for (int j = 0; j < NJ; ++j) {
        int r = wcol + j * 16 + l15;
        boff[j] = (r * 4 + (quad ^ ((r >> 1) & 3))) * 8;
    }

    f32x4 acc[MI][NJ];
#pragma unroll
    for (int i = 0; i < MI; i++)
#pragma unroll
        for (int j = 0; j < NJ; j++) acc[i][j] = (f32x4){0.f, 0.f, 0.f, 0.f};

    for (int k0 = 0; k0 < K; k0 += BK) {
#pragma unroll
        for (int p = 0; p < PA; ++p) {
            GLD16(gAh[p], AsH + lA[p]);
            gAh[p] += BK;
            if constexpr (SPLIT) { GLD16(gAl[p], AsL + lA[p]); gAl[p] += BK; }
        }
#pragma unroll
        for (int p = 0; p < PB; ++p) {
            GLD16(gBh[p], BsH + lB[p]);
            gBh[p] += BK;
            if constexpr (SPLIT) { GLD16(gBl[p], BsL + lB[p]); gBl[p] += BK; }
        }
        __syncthreads();

        bf16x8 aH[MI], bH[NJ];
#pragma unroll
        for (int i = 0; i < MI; ++i) aH[i] = *(const bf16x8*)&AsH[aoff[i]];
#pragma unroll
        for (int j = 0; j < NJ; ++j) bH[j] = *(const bf16x8*)&BsH[boff[j]];
        if constexpr (SPLIT) {
            bf16x8 aL[MI], bL[NJ];
#pragma unroll
            for (int i = 0; i < MI; ++i) aL[i] = *(const bf16x8*)&AsL[aoff[i]];
#pragma unroll
            for (int j = 0; j < NJ; ++j) bL[j] = *(const bf16x8*)&BsL[boff[j]];
#pragma unroll
            for (int i = 0; i < MI; ++i)
#pragma unroll
                for (int j = 0; j < NJ; ++j) {
                    acc[i][j] = __builtin_amdgcn_mfma_f32_16x16x32_bf16(aH[i], bH[j], acc[i][j], 0, 0, 0);
                    acc[i][j] = __builtin_amdgcn_mfma_f32_16x16x32_bf16(aH[i], bL[j], acc[i][j], 0, 0, 0);
                    acc[i][j] = __builtin_amdgcn_mfma_f32_16x16x32_bf16(aL[i], bH[j], acc[i][j], 0, 0, 0);
                }
        } else {
#pragma unroll
            for (int i = 0; i < MI; ++i)
#pragma unroll
                for (int j = 0; j < NJ; ++j)
                    acc[i][j] = __builtin_amdgcn_mfma_f32_16x16x32_bf16(aH[i], bH[j], acc[i][j], 0, 0, 0);
        }
        __syncthreads();
    }

    // epilogue: C/D layout col=lane&15, row=quad*4+reg
#pragma unroll
    for (int i = 0; i < MI; ++i) {
#pragma unroll
        for (int j = 0; j < NJ; ++j) {
            const int mBase = m0 + wrow + i * 16 + quad * 4;
            const int nn = n0 + wcol + j * 16 + l15;
            const bool norm = nn < nsplit;
            float bvs;
            if (norm) bvs = bias1 ? bias1[nn] : 0.f;
            else bvs = bias2 ? bias2[nn - nsplit] : 0.f;
#pragma unroll
            for (int r = 0; r < 4; ++r) {
                const long row = mBase + r;
                float x = acc[i][j][r] * scale + bvs;
                if (resid) x += resid[row * ldres + nn];
                if (norm) {
                    if (Cf) Cf[row * ldcf + nn] = x;
                    if (Cbh) {
                        u16 h = f2bf(x);
                        Cbh[row * ldcb + nn] = h;
                        if (Cbl) Cbl[row * ldcb + nn] = f2bf(x - bf2f(h));
                    }
                } else {
                    long b = row / tRows, q = row - b * tRows;
                    CbT[(b * tChans + (nn - nsplit)) * ldct + q] = f2bf(x);
                }
            }
        }
    }
}

extern "C" void kernel_launch(void* const* d_in, const int* in_sizes, int n_in,
                              void* d_out, int out_size, void* d_ws, size_t ws_size,
                              hipStream_t stream) {
    const float* query = (const float*)d_in[0];
    const float* kv    = (const float*)d_in[1];
    const float* Wq = (const float*)d_in[2];
    const float* bq = (const float*)d_in[3];
    const float* Wk = (const float*)d_in[4];
    const float* Wv = (const float*)d_in[6];
    const float* bv = (const float*)d_in[7];
    const float* Wo = (const float*)d_in[8];
    const float* bo = (const float*)d_in[9];
    float* out = (float*)d_out;

    const int B = 4, N = 2048, D = 512;
    const long MD = (long)B * N * D;  // 4,194,304 (8192 rows x 512)
    const long DD = (long)D * D;
    const int BIG = 1 << 30;

    char* p = (char*)d_ws;
    auto alloc = [&](size_t bytes) { void* r = (void*)p; p += (bytes + 255) & ~(size_t)255; return r; };
    float* S = (float*)alloc((long)B * N * N * 4);   // 67 MB; Xq hi/lo splits alias first 33.5 MB
    u16* QXh = (u16*)S;                               // dead before S is written
    u16* QXl = QXh + MD;
    u16* KVh = (u16*)alloc(MD * 2);                   // alive through S-GEMM + Vproj
    u16* KVl = (u16*)alloc(MD * 2);
    u16* Th  = (u16*)alloc(MD * 2);                   // T = Xq @ G, hi/lo
    u16* Tl  = (u16*)alloc(MD * 2);
    u16* Vt  = (u16*)alloc(MD * 2);                   // [B][D][N]
    u16* Oh  = (u16*)alloc(MD * 2);
    u16* Wqh = (u16*)alloc(DD * 2);                   // split(Wq), ORIGINAL [d][a] layout
    u16* Wql = (u16*)alloc(DD * 2);
    u16* Wkh = (u16*)alloc(DD * 2);
    u16* Wkl = (u16*)alloc(DD * 2);
    u16* WvTh = (u16*)alloc(DD * 2);
    u16* WoTh = (u16*)alloc(DD * 2);
    u16* MTh  = (u16*)alloc(DD * 2);                  // MT[n][k] = G[k][n], G = Wq·Wk^T
    u16* MTl  = (u16*)alloc(DD * 2);
    float* u2 = (float*)alloc(D * 4);
    float* betav = (float*)alloc((long)B * N * 4);    // SCALE * Xk·(Wk bq)

    const dim3 blk(256, 1, 1);
    const float SCALE = 22.627416997969522f;  // sqrt(512), multiplied per reference

    // both input splits in one dispatch + fused weight prep + beta
    split2x2_k<<<dim3(8192, 1, 1), blk, 0, stream>>>(query, QXh, QXl, kv, KVh, KVl, MD / 4);
    prep_weights_k<<<dim3(1026, 1, 1), blk, 0, stream>>>(
        Wq, Wk, Wv, Wo, bq, Wqh, Wql, Wkh, Wkl, WvTh, WoTh, u2, D);
    rowdot_k<<<dim3(2048, 1, 1), blk, 0, stream>>>(kv, u2, betav, D, SCALE);

    // MT = Wk @ Wq^T over attn dim: MT[n][k] = sum_a Wk[n][a]·Wq[k][a] = G[k][n]
    gemm_k<1, 64, 64, 2, 2><<<dim3(8, 8, 1), blk, 0, stream>>>(
        Wkh, Wkl, D, 0,
        Wqh, Wql, D, 0,
        nullptr, nullptr, BIG,
        nullptr, 0, 1.0f,
        nullptr, 0,
        MTh, MTl, D,
        nullptr, 1, 1, 1,
        0, D);
    // T = Xq @ G  (split): BT[n][k] = G[k][n] = MT   (512 blocks, 2/CU)
    gemm_k<1, 128, 64, 2, 2><<<dim3(64, 8, 1), blk, 0, stream>>>(
        QXh, QXl, D, 0,
        MTh, MTl, D, 0,
        nullptr, nullptr, BIG,
        nullptr, 0, 1.0f,
        nullptr, 0,
        Th, Tl, D,
        nullptr, 1, 1, 1,
        0, D);
    // V = Xk @ Wv + bv  (plain), written transposed per batch: Vt[b][c][q]  (512 blocks)
    gemm_k<0, 128, 64, 2, 2><<<dim3(64, 8, 1), blk, 0, stream>>>(
        KVh, nullptr, D, 0,
        WvTh, nullptr, D, 0,
        nullptr, bv, 0,
        nullptr, 0, 1.0f,
        nullptr, 0,
        nullptr, nullptr, 0,
        Vt, (long)N, (long)D, (long)N,
        0, D);
    // S = SCALE * (T @ Xk^T)   (split; beta_j added in softmax, alpha_i cancels)
    gemm_k<1, 128, 128, 2, 2><<<dim3(16, 16, 4), blk, 0, stream>>>(
        Th, Tl, D, (long)N * D,
        KVh, KVl, D, (long)N * D,
        nullptr, nullptr, BIG,
        nullptr, 0, SCALE,
        S, N,
        nullptr, nullptr, 0,
        nullptr, 1, 1, 1,
        (long)N * N, D);
    // softmax rows (+beta_j), bf16 P in place
    softmax_k<<<dim3(B * N, 1, 1), blk, 0, stream>>>(S, betav, N);
    // O = P @ V  (A = bf16 P rows at pitch 2N u16; BT = Vt)  (1024 blocks, 4/CU)
    gemm_k<0, 64, 64, 2, 2><<<dim3(32, 8, 4), blk, 0, stream>>>(
        (const u16*)S, nullptr, 2L * N, (long)N * 2 * N,
        Vt, nullptr, N, (long)D * N,
        nullptr, nullptr, BIG,
        nullptr, 0, 1.0f,
        nullptr, 0,
        Oh, nullptr, D,
        nullptr, 1, 1, 1,
        (long)N * D, N);
    // out = query + O @ Wo + bo   (512 blocks)
    gemm_k<0, 128, 64, 2, 2><<<dim3(64, 8, 1), blk, 0, stream>>>(
        Oh, nullptr, D, 0,
        WoTh, nullptr, D, 0,
        bo, nullptr, BIG,
        query, D, 1.0f,
        out, D,
        nullptr, nullptr, 0,
        nullptr, 1, 1, 1,
        0, D);
    (void)in_sizes; (void)n_in; (void)out_size; (void)ws_size;
}